// Round 3
// baseline (99.896 us; speedup 1.0000x reference)
//
#include <hip/hip_runtime.h>
#include <math.h>

#define BATCH 4
#define NPTS 8192
#define TPB 256
#define RPT 8                              // rows per thread (16B LDS / col / thread amortized over 8 rows)
#define ROWS_PER_BLOCK (TPB * RPT)         // 2048
#define ROW_TILES (NPTS / ROWS_PER_BLOCK)  // 4

// One row's min-update over two staged columns (ya, yb):
// 6 v_fma_f32 + 1 v_min3_f32 for 2 (row,col) pairs.
#define ROW2(mn, x0_, x1_, x2_)                                     \
  do {                                                              \
    float ta = __builtin_fmaf((x0_), ya.x, ya.w);                   \
    ta = __builtin_fmaf((x1_), ya.y, ta);                           \
    ta = __builtin_fmaf((x2_), ya.z, ta);                           \
    float tb = __builtin_fmaf((x0_), yb.x, yb.w);                   \
    tb = __builtin_fmaf((x1_), yb.y, tb);                           \
    tb = __builtin_fmaf((x2_), yb.z, tb);                           \
    asm("v_min3_f32 %0, %0, %1, %2" : "+v"(mn) : "v"(ta), "v"(tb)); \
  } while (0)

#define LOADX(i, off)                                                       \
  const float* p##i = rows + ((size_t)b * NPTS + rowBase + (off) + tid) * 3; \
  const float x##i##0 = p##i[0], x##i##1 = p##i[1], x##i##2 = p##i[2];      \
  const float n##i =                                                        \
      x##i##0 * x##i##0 + x##i##1 * x##i##1 + x##i##2 * x##i##2;            \
  float mn##i = INFINITY;

// Kernel 1: partial row-mins of squared distance.
// grid = (ROW_TILES * S, BATCH, 2); block = TPB; 2 blocks/CU.
// R2 post-mortem: at RPT=4 the kernel was LDS-return-BW-bound
// (16 waves/CU x 512 cols x 1024 B/wave-read = 8.4 MB/CU ~= 99k cyc at
// 85 B/cyc vs 113.9k measured). RPT=8 halves LDS bytes/pair -> VALU-bound.
__global__ __launch_bounds__(TPB, 2) void chamfer_partial(
    const float* __restrict__ pred, const float* __restrict__ label,
    float* __restrict__ ws, float* __restrict__ out, int S, int colsPerSeg) {
  const int tid = threadIdx.x;
  const int seg = blockIdx.x % S;
  const int rowTile = blockIdx.x / S;
  const int b = blockIdx.y;
  const int dir = blockIdx.z;
  const float* __restrict__ rows = (dir == 0) ? pred : label;
  const float* __restrict__ cols = (dir == 0) ? label : pred;

  // Zero the output scalar once (stream-ordered before chamfer_reduce's
  // atomics) -- replaces a separate memset dispatch.
  if (blockIdx.x == 0 && b == 0 && dir == 0 && tid == 0) out[0] = 0.0f;

  const int rowBase = rowTile * ROWS_PER_BLOCK;
  LOADX(0, 0 * TPB)
  LOADX(1, 1 * TPB)
  LOADX(2, 2 * TPB)
  LOADX(3, 3 * TPB)
  LOADX(4, 4 * TPB)
  LOADX(5, 5 * TPB)
  LOADX(6, 6 * TPB)
  LOADX(7, 7 * TPB)

  __shared__ float4 sh[TPB];
  const int colBase = seg * colsPerSeg;
  for (int c0 = 0; c0 < colsPerSeg; c0 += TPB) {
    __syncthreads();
    {
      const int col = colBase + c0 + tid;
      const float* q = cols + ((size_t)b * NPTS + col) * 3;
      const float y0 = q[0], y1 = q[1], y2 = q[2];
      sh[tid] = make_float4(-2.0f * y0, -2.0f * y1, -2.0f * y2,
                            y0 * y0 + y1 * y1 + y2 * y2);
    }
    __syncthreads();
#pragma unroll 4
    for (int l = 0; l < TPB; l += 2) {
      const float4 ya = sh[l];
      const float4 yb = sh[l + 1];
      ROW2(mn0, x00, x01, x02);
      ROW2(mn1, x10, x11, x12);
      ROW2(mn2, x20, x21, x22);
      ROW2(mn3, x30, x31, x32);
      ROW2(mn4, x40, x41, x42);
      ROW2(mn5, x50, x51, x52);
      ROW2(mn6, x60, x61, x62);
      ROW2(mn7, x70, x71, x72);
    }
  }

  float* w = ws + (((size_t)dir * BATCH + b) * S + seg) * NPTS + rowBase + tid;
  w[0 * TPB] = n0 + mn0;
  w[1 * TPB] = n1 + mn1;
  w[2 * TPB] = n2 + mn2;
  w[3 * TPB] = n3 + mn3;
  w[4 * TPB] = n4 + mn4;
  w[5 * TPB] = n5 + mn5;
  w[6 * TPB] = n6 + mn6;
  w[7 * TPB] = n7 + mn7;
}

// Kernel 2: per row, min over the S segment-partials (unrolled ->
// independent coalesced loads), clamp, sqrt, scale, block-reduce,
// one atomicAdd per block. grid = 256 x 256, 1 row/thread -> 65536 rows
// (R2's 64-block version occupied only 25% of CUs, latency-bound).
template <int S>
__global__ __launch_bounds__(256) void chamfer_reduce(
    const float* __restrict__ ws, float* __restrict__ out) {
  const int g = blockIdx.x * 256 + threadIdx.x;  // 0..65535
  const int db = g >> 13;                        // dir*BATCH+b, 0..7
  const int row = g & (NPTS - 1);
  const float* p = ws + (size_t)db * S * NPTS + row;
  float m = INFINITY;
#pragma unroll
  for (int s = 0; s < S; ++s) m = fminf(m, p[(size_t)s * NPTS]);
  float sum = sqrtf(fmaxf(m, 0.0f)) * (1.0f / (float)(BATCH * NPTS));
  for (int off = 32; off > 0; off >>= 1) sum += __shfl_down(sum, off, 64);
  __shared__ float ssum[4];
  const int wid = threadIdx.x >> 6;
  const int lane = threadIdx.x & 63;
  if (lane == 0) ssum[wid] = sum;
  __syncthreads();
  if (threadIdx.x == 0) atomicAdd(out, ssum[0] + ssum[1] + ssum[2] + ssum[3]);
}

extern "C" void kernel_launch(void* const* d_in, const int* in_sizes, int n_in,
                              void* d_out, int out_size, void* d_ws,
                              size_t ws_size, hipStream_t stream) {
  const float* pred = (const float*)d_in[0];
  const float* label = (const float*)d_in[1];
  float* out = (float*)d_out;
  float* ws = (float*)d_ws;

  // Segment count chosen to fit workspace: need 2*BATCH*S*NPTS floats (4 MB
  // at S=16; R2's poison fill shows ws ~= 256 MB, so S=16 holds).
  int S = 16;
  while (S > 1 && (size_t)2 * BATCH * S * NPTS * sizeof(float) > ws_size)
    S >>= 1;
  const int colsPerSeg = NPTS / S;

  dim3 grid1(ROW_TILES * S, BATCH, 2);
  chamfer_partial<<<grid1, TPB, 0, stream>>>(pred, label, ws, out, S,
                                             colsPerSeg);
  switch (S) {
    case 16: chamfer_reduce<16><<<256, 256, 0, stream>>>(ws, out); break;
    case 8:  chamfer_reduce<8><<<256, 256, 0, stream>>>(ws, out); break;
    case 4:  chamfer_reduce<4><<<256, 256, 0, stream>>>(ws, out); break;
    case 2:  chamfer_reduce<2><<<256, 256, 0, stream>>>(ws, out); break;
    default: chamfer_reduce<1><<<256, 256, 0, stream>>>(ws, out); break;
  }
}